// Round 3
// baseline (5186.678 us; speedup 1.0000x reference)
//
#include <hip/hip_runtime.h>
#include <hip/hip_bf16.h>

#define BB 128
#define TT 25
#define VOCAB 10000
#define HIDD 512

typedef __hip_bfloat16 bf16;

__device__ __forceinline__ float sigmoidf_(float x) { return 1.0f / (1.0f + __expf(-x)); }

__device__ __forceinline__ float4 f4_fma(float s, float4 w, float4 a) {
    a.x += s * w.x; a.y += s * w.y; a.z += s * w.z; a.w += s * w.w;
    return a;
}

// =====================================================================
// h0 = tanh(vgg @ W_in + b_in): M=128, K=4096, N=512. grid (8,8)
// =====================================================================
__global__ __launch_bounds__(256) void k_h0(const float* __restrict__ A,
                                            const float* __restrict__ W,
                                            const float* __restrict__ bias,
                                            float* __restrict__ o1,
                                            float* __restrict__ o2)
{
    __shared__ float As[16][68];
    __shared__ float Bs[64][68];
    const int tid = threadIdx.x;
    const int tx = tid & 15, ty = tid >> 4;
    const int n0 = blockIdx.x * 64, m0 = blockIdx.y * 16;
    float acc[4] = {0.f, 0.f, 0.f, 0.f};

    for (int k0 = 0; k0 < 4096; k0 += 64) {
        *(float4*)&As[ty][tx * 4] =
            *(const float4*)&A[(size_t)(m0 + ty) * 4096 + k0 + tx * 4];
        #pragma unroll
        for (int l = 0; l < 4; ++l) {
            int idx = tid + l * 256;
            int r = idx >> 4, c = (idx & 15) * 4;
            *(float4*)&Bs[r][c] = *(const float4*)&W[(size_t)(k0 + r) * 512 + n0 + c];
        }
        __syncthreads();
        #pragma unroll 8
        for (int kk = 0; kk < 64; ++kk) {
            float a = As[ty][kk];
            float4 b = *(float4*)&Bs[kk][tx * 4];
            acc[0] += a * b.x; acc[1] += a * b.y;
            acc[2] += a * b.z; acc[3] += a * b.w;
        }
        __syncthreads();
    }
    int m = m0 + ty, n = n0 + tx * 4;
    float4 r4;
    r4.x = tanhf(acc[0] + bias[n + 0]);
    r4.y = tanhf(acc[1] + bias[n + 1]);
    r4.z = tanhf(acc[2] + bias[n + 2]);
    r4.w = tanhf(acc[3] + bias[n + 3]);
    *(float4*)&o1[m * 512 + n] = r4;
    *(float4*)&o2[m * 512 + n] = r4;
}

// =====================================================================
// X0 precompute: X0[m][n] = emb[tok(m)] @ {Wu0|Wr0|Wc0}[0:512] + bias
//   m = t*128 + b, tok(m) = toks[b*TT + t]; n in [0,1536)
// BM=64, BN=64, BK=32, 4x4 thread tile. grid (24, 50).
// =====================================================================
__global__ __launch_bounds__(256) void k_x0pre(const float* __restrict__ emb,
                                               const int* __restrict__ toks,
                                               const float* __restrict__ Wu0,
                                               const float* __restrict__ bu0,
                                               const float* __restrict__ Wr0,
                                               const float* __restrict__ br0,
                                               const float* __restrict__ Wc0,
                                               const float* __restrict__ bc0,
                                               float* __restrict__ X0)
{
    __shared__ float As[64][36];
    __shared__ float Bs[32][68];
    const int tid = threadIdx.x;
    const int tx = tid & 15, ty = tid >> 4;
    const int n0 = blockIdx.x * 64, m0 = blockIdx.y * 64;
    const int seg = n0 >> 9;                 // 0:u 1:r 2:c
    const float* W    = seg == 0 ? Wu0 : (seg == 1 ? Wr0 : Wc0);
    const float* bias = seg == 0 ? bu0 : (seg == 1 ? br0 : bc0);
    const int col0 = n0 & 511;

    float acc[4][4];
    #pragma unroll
    for (int i = 0; i < 4; ++i)
        #pragma unroll
        for (int j = 0; j < 4; ++j) acc[i][j] = 0.f;

    for (int k0 = 0; k0 < 512; k0 += 32) {
        #pragma unroll
        for (int l = 0; l < 2; ++l) {
            int idx = tid + l * 256;
            int r = idx >> 3, c = (idx & 7) * 4;
            int m = m0 + r;
            int tok = toks[(m & 127) * TT + (m >> 7)];
            *(float4*)&As[r][c] = *(const float4*)&emb[(size_t)tok * 512 + k0 + c];
        }
        #pragma unroll
        for (int l = 0; l < 2; ++l) {
            int idx = tid + l * 256;
            int r = idx >> 4, c = (idx & 15) * 4;
            *(float4*)&Bs[r][c] = *(const float4*)&W[(size_t)(k0 + r) * 512 + col0 + c];
        }
        __syncthreads();
        #pragma unroll 4
        for (int kk = 0; kk < 32; ++kk) {
            float4 b = *(float4*)&Bs[kk][tx * 4];
            float a0 = As[ty * 4 + 0][kk];
            float a1 = As[ty * 4 + 1][kk];
            float a2 = As[ty * 4 + 2][kk];
            float a3 = As[ty * 4 + 3][kk];
            acc[0][0] += a0 * b.x; acc[0][1] += a0 * b.y; acc[0][2] += a0 * b.z; acc[0][3] += a0 * b.w;
            acc[1][0] += a1 * b.x; acc[1][1] += a1 * b.y; acc[1][2] += a1 * b.z; acc[1][3] += a1 * b.w;
            acc[2][0] += a2 * b.x; acc[2][1] += a2 * b.y; acc[2][2] += a2 * b.z; acc[2][3] += a2 * b.w;
            acc[3][0] += a3 * b.x; acc[3][1] += a3 * b.y; acc[3][2] += a3 * b.z; acc[3][3] += a3 * b.w;
        }
        __syncthreads();
    }

    int nc = col0 + tx * 4;
    float b0 = bias[nc + 0], b1 = bias[nc + 1], b2 = bias[nc + 2], b3 = bias[nc + 3];
    #pragma unroll
    for (int i = 0; i < 4; ++i) {
        int m = m0 + ty * 4 + i;
        float4 r4;
        r4.x = acc[i][0] + b0; r4.y = acc[i][1] + b1;
        r4.z = acc[i][2] + b2; r4.w = acc[i][3] + b3;
        *(float4*)&X0[(size_t)m * 1536 + n0 + tx * 4] = r4;
    }
}

// =====================================================================
// Streaming phase kernels: out[128, N] = A[128,512] @ W(K=512 slice) + ...
// Block: 256 thr (lane=tid&63 covers 256 n-cols as float4; ty=tid>>6 = m).
// A rows staged in LDS as float4; W streamed from global (L2-resident).
// =====================================================================

// L0 gates: pre = h @ {Wu0|Wr0}[512:1024] + X0t[:, n]; sigmoid -> gu|gr
// grid (4, 32)
__global__ __launch_bounds__(256) void k_p1l0(const float* __restrict__ h,
                                              const float* __restrict__ X0t,
                                              const float* __restrict__ Wu0,
                                              const float* __restrict__ Wr0,
                                              float* __restrict__ gu,
                                              float* __restrict__ gr)
{
    __shared__ float4 hA[4][128];
    const int tid = threadIdx.x;
    const int lane = tid & 63, ty = tid >> 6;
    const int n0 = blockIdx.x * 256, m0 = blockIdx.y * 4;
    #pragma unroll
    for (int l = 0; l < 2; ++l) {
        int idx = tid + l * 256;
        int r = idx >> 7, c = idx & 127;
        hA[r][c] = *(const float4*)&h[(size_t)(m0 + r) * 512 + c * 4];
    }
    __syncthreads();

    const int n = n0 + lane * 4;
    const int ncol = n & 511;
    const float* Wp = (n0 < 512 ? Wu0 : Wr0) + (size_t)512 * 512 + ncol;
    float4 acc = {0.f, 0.f, 0.f, 0.f};
    for (int k = 0; k < 512; k += 4) {
        float4 a = hA[ty][k >> 2];
        float4 w0 = *(const float4*)(Wp + (size_t)(k + 0) * 512);
        float4 w1 = *(const float4*)(Wp + (size_t)(k + 1) * 512);
        float4 w2 = *(const float4*)(Wp + (size_t)(k + 2) * 512);
        float4 w3 = *(const float4*)(Wp + (size_t)(k + 3) * 512);
        acc = f4_fma(a.x, w0, acc);
        acc = f4_fma(a.y, w1, acc);
        acc = f4_fma(a.z, w2, acc);
        acc = f4_fma(a.w, w3, acc);
    }
    const int m = m0 + ty;
    float4 xp = *(const float4*)&X0t[(size_t)m * 1536 + n];
    float4 r4;
    r4.x = sigmoidf_(acc.x + xp.x);
    r4.y = sigmoidf_(acc.y + xp.y);
    r4.z = sigmoidf_(acc.z + xp.z);
    r4.w = sigmoidf_(acc.w + xp.w);
    float* out = (n0 < 512 ? gu : gr);
    *(float4*)&out[(size_t)m * 512 + ncol] = r4;
}

// L0 cand+combine: hh = tanh((gr*h) @ Wc0[512:] + X0t[:,1024+n]);
//                  s0out = gu*h + (1-gu)*hh.   grid (2, 32)
__global__ __launch_bounds__(256) void k_p2l0(const float* __restrict__ h,
                                              const float* __restrict__ gu,
                                              const float* __restrict__ gr,
                                              const float* __restrict__ X0t,
                                              const float* __restrict__ Wc0,
                                              float* __restrict__ s0out)
{
    __shared__ float4 hA[4][128];
    const int tid = threadIdx.x;
    const int lane = tid & 63, ty = tid >> 6;
    const int n0 = blockIdx.x * 256, m0 = blockIdx.y * 4;
    #pragma unroll
    for (int l = 0; l < 2; ++l) {
        int idx = tid + l * 256;
        int r = idx >> 7, c = idx & 127;
        float4 hv = *(const float4*)&h[(size_t)(m0 + r) * 512 + c * 4];
        float4 gv = *(const float4*)&gr[(size_t)(m0 + r) * 512 + c * 4];
        hv.x *= gv.x; hv.y *= gv.y; hv.z *= gv.z; hv.w *= gv.w;
        hA[r][c] = hv;
    }
    __syncthreads();

    const int n = n0 + lane * 4;
    const float* Wp = Wc0 + (size_t)512 * 512 + n;
    float4 acc = {0.f, 0.f, 0.f, 0.f};
    for (int k = 0; k < 512; k += 4) {
        float4 a = hA[ty][k >> 2];
        float4 w0 = *(const float4*)(Wp + (size_t)(k + 0) * 512);
        float4 w1 = *(const float4*)(Wp + (size_t)(k + 1) * 512);
        float4 w2 = *(const float4*)(Wp + (size_t)(k + 2) * 512);
        float4 w3 = *(const float4*)(Wp + (size_t)(k + 3) * 512);
        acc = f4_fma(a.x, w0, acc);
        acc = f4_fma(a.y, w1, acc);
        acc = f4_fma(a.z, w2, acc);
        acc = f4_fma(a.w, w3, acc);
    }
    const int m = m0 + ty;
    float4 xp = *(const float4*)&X0t[(size_t)m * 1536 + 1024 + n];
    float4 g  = *(const float4*)&gu[(size_t)m * 512 + n];
    float4 hv = *(const float4*)&h[(size_t)m * 512 + n];
    float4 r4;
    r4.x = g.x * hv.x + (1.f - g.x) * tanhf(acc.x + xp.x);
    r4.y = g.y * hv.y + (1.f - g.y) * tanhf(acc.y + xp.y);
    r4.z = g.z * hv.z + (1.f - g.z) * tanhf(acc.z + xp.z);
    r4.w = g.w * hv.w + (1.f - g.w) * tanhf(acc.w + xp.w);
    *(float4*)&s0out[(size_t)m * 512 + n] = r4;
}

// L1 gates + cand-top: A = [s0new | h1] (K=1024).
//   n<1024:  pre = A @ {Wu1|Wr1} + b -> sigmoid -> gu|gr
//   n>=1024: cpre = s0new @ Wc1[0:512] + bc1 (K=512, raw)
// grid (6, 32)
__global__ __launch_bounds__(256) void k_p1l1(const float* __restrict__ s0n,
                                              const float* __restrict__ h1,
                                              const float* __restrict__ Wu1,
                                              const float* __restrict__ bu1,
                                              const float* __restrict__ Wr1,
                                              const float* __restrict__ br1,
                                              const float* __restrict__ Wc1,
                                              const float* __restrict__ bc1,
                                              float* __restrict__ gu,
                                              float* __restrict__ gr,
                                              float* __restrict__ cpre)
{
    __shared__ float4 hA[4][256];   // 16 KB: [s0n row | h1 row]
    const int tid = threadIdx.x;
    const int lane = tid & 63, ty = tid >> 6;
    const int n0 = blockIdx.x * 256, m0 = blockIdx.y * 4;
    #pragma unroll
    for (int l = 0; l < 4; ++l) {
        int idx = tid + l * 256;
        int r = idx >> 8, c = idx & 255;
        const float* src = (c < 128) ? &s0n[(size_t)(m0 + r) * 512 + c * 4]
                                     : &h1[(size_t)(m0 + r) * 512 + (c - 128) * 4];
        hA[r][c] = *(const float4*)src;
    }
    __syncthreads();

    const int seg = blockIdx.x >> 1;   // 0:u 1:r 2:c
    const int n = n0 + lane * 4;
    const int ncol = n & 511;
    const float* W    = seg == 0 ? Wu1 : (seg == 1 ? Wr1 : Wc1);
    const float* bias = seg == 0 ? bu1 : (seg == 1 ? br1 : bc1);
    const float* Wp = W + ncol;
    const int kmax = (seg < 2) ? 1024 : 512;
    float4 acc = {0.f, 0.f, 0.f, 0.f};
    for (int k = 0; k < kmax; k += 4) {
        float4 a = hA[ty][k >> 2];
        float4 w0 = *(const float4*)(Wp + (size_t)(k + 0) * 512);
        float4 w1 = *(const float4*)(Wp + (size_t)(k + 1) * 512);
        float4 w2 = *(const float4*)(Wp + (size_t)(k + 2) * 512);
        float4 w3 = *(const float4*)(Wp + (size_t)(k + 3) * 512);
        acc = f4_fma(a.x, w0, acc);
        acc = f4_fma(a.y, w1, acc);
        acc = f4_fma(a.z, w2, acc);
        acc = f4_fma(a.w, w3, acc);
    }
    const int m = m0 + ty;
    float4 bv = *(const float4*)&bias[ncol];
    acc.x += bv.x; acc.y += bv.y; acc.z += bv.z; acc.w += bv.w;
    if (seg < 2) {
        float4 r4;
        r4.x = sigmoidf_(acc.x); r4.y = sigmoidf_(acc.y);
        r4.z = sigmoidf_(acc.z); r4.w = sigmoidf_(acc.w);
        float* out = (seg == 0 ? gu : gr);
        *(float4*)&out[(size_t)m * 512 + ncol] = r4;
    } else {
        *(float4*)&cpre[(size_t)m * 512 + ncol] = acc;
    }
}

// L1 cand+combine: hh = tanh((gr*h1) @ Wc1[512:] + cpre);
//                  s1out = gu*h1 + (1-gu)*hh; also -> s1all_t.  grid (2, 32)
__global__ __launch_bounds__(256) void k_p2l1(const float* __restrict__ h1,
                                              const float* __restrict__ gu,
                                              const float* __restrict__ gr,
                                              const float* __restrict__ cpre,
                                              const float* __restrict__ Wc1,
                                              float* __restrict__ s1out,
                                              float* __restrict__ s1all_t)
{
    __shared__ float4 hA[4][128];
    const int tid = threadIdx.x;
    const int lane = tid & 63, ty = tid >> 6;
    const int n0 = blockIdx.x * 256, m0 = blockIdx.y * 4;
    #pragma unroll
    for (int l = 0; l < 2; ++l) {
        int idx = tid + l * 256;
        int r = idx >> 7, c = idx & 127;
        float4 hv = *(const float4*)&h1[(size_t)(m0 + r) * 512 + c * 4];
        float4 gv = *(const float4*)&gr[(size_t)(m0 + r) * 512 + c * 4];
        hv.x *= gv.x; hv.y *= gv.y; hv.z *= gv.z; hv.w *= gv.w;
        hA[r][c] = hv;
    }
    __syncthreads();

    const int n = n0 + lane * 4;
    const float* Wp = Wc1 + (size_t)512 * 512 + n;
    float4 acc = {0.f, 0.f, 0.f, 0.f};
    for (int k = 0; k < 512; k += 4) {
        float4 a = hA[ty][k >> 2];
        float4 w0 = *(const float4*)(Wp + (size_t)(k + 0) * 512);
        float4 w1 = *(const float4*)(Wp + (size_t)(k + 1) * 512);
        float4 w2 = *(const float4*)(Wp + (size_t)(k + 2) * 512);
        float4 w3 = *(const float4*)(Wp + (size_t)(k + 3) * 512);
        acc = f4_fma(a.x, w0, acc);
        acc = f4_fma(a.y, w1, acc);
        acc = f4_fma(a.z, w2, acc);
        acc = f4_fma(a.w, w3, acc);
    }
    const int m = m0 + ty;
    float4 cp = *(const float4*)&cpre[(size_t)m * 512 + n];
    float4 g  = *(const float4*)&gu[(size_t)m * 512 + n];
    float4 hv = *(const float4*)&h1[(size_t)m * 512 + n];
    float4 r4;
    r4.x = g.x * hv.x + (1.f - g.x) * tanhf(acc.x + cp.x);
    r4.y = g.y * hv.y + (1.f - g.y) * tanhf(acc.y + cp.y);
    r4.z = g.z * hv.z + (1.f - g.z) * tanhf(acc.z + cp.z);
    r4.w = g.w * hv.w + (1.f - g.w) * tanhf(acc.w + cp.w);
    *(float4*)&s1out[(size_t)m * 512 + n] = r4;
    *(float4*)&s1all_t[(size_t)m * 512 + n] = r4;
}

// =====================================================================
// logits: out[b,t,:] = s1all[t*128+b,:] @ Wout + bout (unchanged)
// =====================================================================
__global__ __launch_bounds__(256) void k_logits(const float* __restrict__ A,
                                                const float* __restrict__ W,
                                                const float* __restrict__ bias,
                                                float* __restrict__ out)
{
    __shared__ float As[64][36];
    __shared__ float Bs[32][68];
    const int tid = threadIdx.x;
    const int tx = tid & 15, ty = tid >> 4;
    const int n0 = blockIdx.x * 64, m0 = blockIdx.y * 64;
    float acc[4][4];
    #pragma unroll
    for (int i = 0; i < 4; ++i)
        #pragma unroll
        for (int j = 0; j < 4; ++j) acc[i][j] = 0.f;

    for (int k0 = 0; k0 < 512; k0 += 32) {
        #pragma unroll
        for (int l = 0; l < 2; ++l) {
            int idx = tid + l * 256;
            int r = idx >> 3, c = (idx & 7) * 4;
            *(float4*)&As[r][c] = *(const float4*)&A[(size_t)(m0 + r) * 512 + k0 + c];
        }
        #pragma unroll
        for (int l = 0; l < 2; ++l) {
            int idx = tid + l * 256;
            int r = idx >> 4, c = (idx & 15) * 4;
            int gcol = n0 + c;
            float4 bv = {0.f, 0.f, 0.f, 0.f};
            if (gcol < VOCAB)
                bv = *(const float4*)&W[(size_t)(k0 + r) * VOCAB + gcol];
            *(float4*)&Bs[r][c] = bv;
        }
        __syncthreads();
        #pragma unroll 4
        for (int kk = 0; kk < 32; ++kk) {
            float4 b = *(float4*)&Bs[kk][tx * 4];
            float a0 = As[ty * 4 + 0][kk];
            float a1 = As[ty * 4 + 1][kk];
            float a2 = As[ty * 4 + 2][kk];
            float a3 = As[ty * 4 + 3][kk];
            acc[0][0] += a0 * b.x; acc[0][1] += a0 * b.y; acc[0][2] += a0 * b.z; acc[0][3] += a0 * b.w;
            acc[1][0] += a1 * b.x; acc[1][1] += a1 * b.y; acc[1][2] += a1 * b.z; acc[1][3] += a1 * b.w;
            acc[2][0] += a2 * b.x; acc[2][1] += a2 * b.y; acc[2][2] += a2 * b.z; acc[2][3] += a2 * b.w;
            acc[3][0] += a3 * b.x; acc[3][1] += a3 * b.y; acc[3][2] += a3 * b.z; acc[3][3] += a3 * b.w;
        }
        __syncthreads();
    }

    int n = n0 + tx * 4;
    if (n < VOCAB) {
        float b0 = bias[n + 0], b1 = bias[n + 1], b2 = bias[n + 2], b3 = bias[n + 3];
        #pragma unroll
        for (int i = 0; i < 4; ++i) {
            int m = m0 + ty * 4 + i;
            int tt = m >> 7;
            int bb = m & 127;
            float4 r4;
            r4.x = acc[i][0] + b0; r4.y = acc[i][1] + b1;
            r4.z = acc[i][2] + b2; r4.w = acc[i][3] + b3;
            *(float4*)&out[(size_t)bb * TT * VOCAB + (size_t)tt * VOCAB + n] = r4;
        }
    }
}

__global__ void k_states(const float* __restrict__ s0, const float* __restrict__ s1,
                         float* __restrict__ out)
{
    int i = blockIdx.x * 256 + threadIdx.x;
    if (i < BB * HIDD) {
        out[i] = s0[i];
        out[BB * HIDD + i] = s1[i];
    }
}

extern "C" void kernel_launch(void* const* d_in, const int* in_sizes, int n_in,
                              void* d_out, int out_size, void* d_ws, size_t ws_size,
                              hipStream_t stream)
{
    const float* vgg  = (const float*)d_in[0];
    const int*   toks = (const int*)d_in[1];
    const float* emb  = (const float*)d_in[3];
    const float* Win  = (const float*)d_in[4];
    const float* bin  = (const float*)d_in[5];
    const float* Wu0  = (const float*)d_in[6];
    const float* bu0  = (const float*)d_in[7];
    const float* Wr0  = (const float*)d_in[8];
    const float* br0  = (const float*)d_in[9];
    const float* Wc0  = (const float*)d_in[10];
    const float* bc0  = (const float*)d_in[11];
    const float* Wu1  = (const float*)d_in[12];
    const float* bu1  = (const float*)d_in[13];
    const float* Wr1  = (const float*)d_in[14];
    const float* br1  = (const float*)d_in[15];
    const float* Wc1  = (const float*)d_in[16];
    const float* bc1  = (const float*)d_in[17];
    const float* Wout = (const float*)d_in[18];
    const float* bout = (const float*)d_in[19];

    float* ws = (float*)d_ws;
    float* s0a  = ws;                       // 128*512
    float* s0b  = s0a + BB * HIDD;
    float* s1a  = s0b + BB * HIDD;
    float* s1b  = s1a + BB * HIDD;
    float* gu   = s1b + BB * HIDD;
    float* gr   = gu + BB * HIDD;
    float* cpre = gr + BB * HIDD;
    float* s1all = cpre + BB * HIDD;        // 3200*512
    float* X0    = s1all + (size_t)TT * BB * HIDD;  // 3200*1536

    float* out = (float*)d_out;

    k_h0<<<dim3(8, 8), 256, 0, stream>>>(vgg, Win, bin, s0a, s1a);
    k_x0pre<<<dim3(24, 50), 256, 0, stream>>>(emb, toks, Wu0, bu0, Wr0, br0,
                                              Wc0, bc0, X0);

    for (int t = 0; t < TT; ++t) {
        const float* X0t = X0 + (size_t)t * BB * 1536;
        k_p1l0<<<dim3(4, 32), 256, 0, stream>>>(s0a, X0t, Wu0, Wr0, gu, gr);
        k_p2l0<<<dim3(2, 32), 256, 0, stream>>>(s0a, gu, gr, X0t, Wc0, s0b);
        k_p1l1<<<dim3(6, 32), 256, 0, stream>>>(s0b, s1a, Wu1, bu1, Wr1, br1,
                                                Wc1, bc1, gu, gr, cpre);
        k_p2l1<<<dim3(2, 32), 256, 0, stream>>>(s1a, gu, gr, cpre, Wc1, s1b,
                                                s1all + (size_t)t * BB * HIDD);
        float* tmp;
        tmp = s0a; s0a = s0b; s0b = tmp;
        tmp = s1a; s1a = s1b; s1b = tmp;
    }

    k_logits<<<dim3(157, 50), 256, 0, stream>>>(s1all, Wout, bout, out);

    k_states<<<dim3((BB * HIDD + 255) / 256), 256, 0, stream>>>(
        s0a, s1a, out + (size_t)TT * BB * VOCAB);
}

// Round 4
// 2143.571 us; speedup vs baseline: 2.4196x; 2.4196x over previous
//
#include <hip/hip_runtime.h>
#include <hip/hip_bf16.h>

#define BB 128
#define TT 25
#define VOCAB 10000
#define HIDD 512

typedef __hip_bfloat16 bf16;
typedef short bf16x8 __attribute__((ext_vector_type(8)));
typedef float f32x4 __attribute__((ext_vector_type(4)));

__device__ __forceinline__ float sigmoidf_(float x) { return 1.0f / (1.0f + __expf(-x)); }

__device__ __forceinline__ float4 f4_fma(float s, float4 w, float4 a) {
    a.x += s * w.x; a.y += s * w.y; a.z += s * w.z; a.w += s * w.w;
    return a;
}

__device__ __forceinline__ unsigned short f2bfu(float x) {
    bf16 h = __float2bfloat16(x);
    return *reinterpret_cast<unsigned short*>(&h);
}

// =====================================================================
// h0 = tanh(vgg @ W_in + b_in): M=128, K=4096, N=512. grid (8,8)
// =====================================================================
__global__ __launch_bounds__(256) void k_h0(const float* __restrict__ A,
                                            const float* __restrict__ W,
                                            const float* __restrict__ bias,
                                            float* __restrict__ o1,
                                            float* __restrict__ o2)
{
    __shared__ float As[16][68];
    __shared__ float Bs[64][68];
    const int tid = threadIdx.x;
    const int tx = tid & 15, ty = tid >> 4;
    const int n0 = blockIdx.x * 64, m0 = blockIdx.y * 16;
    float acc[4] = {0.f, 0.f, 0.f, 0.f};

    for (int k0 = 0; k0 < 4096; k0 += 64) {
        *(float4*)&As[ty][tx * 4] =
            *(const float4*)&A[(size_t)(m0 + ty) * 4096 + k0 + tx * 4];
        #pragma unroll
        for (int l = 0; l < 4; ++l) {
            int idx = tid + l * 256;
            int r = idx >> 4, c = (idx & 15) * 4;
            *(float4*)&Bs[r][c] = *(const float4*)&W[(size_t)(k0 + r) * 512 + n0 + c];
        }
        __syncthreads();
        #pragma unroll 8
        for (int kk = 0; kk < 64; ++kk) {
            float a = As[ty][kk];
            float4 b = *(float4*)&Bs[kk][tx * 4];
            acc[0] += a * b.x; acc[1] += a * b.y;
            acc[2] += a * b.z; acc[3] += a * b.w;
        }
        __syncthreads();
    }
    int m = m0 + ty, n = n0 + tx * 4;
    float4 r4;
    r4.x = tanhf(acc[0] + bias[n + 0]);
    r4.y = tanhf(acc[1] + bias[n + 1]);
    r4.z = tanhf(acc[2] + bias[n + 2]);
    r4.w = tanhf(acc[3] + bias[n + 3]);
    *(float4*)&o1[m * 512 + n] = r4;
    *(float4*)&o2[m * 512 + n] = r4;
}

// =====================================================================
// Phase-kernel GEMM core. Thread layout (256 thr):
//   n4 = tid&15 (16 x float4 = 64 cols), mi = (tid>>4)&7 (8 rows),
//   kh = tid>>7 (K-half). Each thread: 4 cols x 1 row x K=512.
// A slabs in LDS (wave-uniform broadcast reads); W streamed from L2
// with 8 loads in flight. Cross-kh reduction via LDS.
// =====================================================================

// W pre-offset to (kh*512)*512 + col. arow = As[kh][mi].
__device__ __forceinline__ float4 core512(const float* __restrict__ Wp,
                                          const float* __restrict__ arow)
{
    float4 acc = {0.f, 0.f, 0.f, 0.f};
    for (int k = 0; k < 512; k += 8) {
        float4 w[8];
        #pragma unroll
        for (int j = 0; j < 8; ++j)
            w[j] = *(const float4*)(Wp + (size_t)(k + j) * 512);
        #pragma unroll
        for (int j = 0; j < 8; ++j)
            acc = f4_fma(arow[k + j], w[j], acc);
    }
    return acc;
}

#define PHASE_PROLOG \
    __shared__ float As[2][8][516]; \
    __shared__ float4 red[256]; \
    const int tid = threadIdx.x; \
    const int n4 = tid & 15, mi = (tid >> 4) & 7, kh = tid >> 7; \
    const int m0 = blockIdx.y * 8;

// L0 gates: gu|gr = sigmoid([emb(tok), h] @ {Wu0|Wr0} + {bu0|br0})
// grid (16, 16): bx>>3 = gate, (bx&7)*64 = col0
__global__ __launch_bounds__(256) void k_p1l0(const float* __restrict__ h,
                                              const float* __restrict__ emb,
                                              const int* __restrict__ toks, int t,
                                              const float* __restrict__ Wu,
                                              const float* __restrict__ bu,
                                              const float* __restrict__ Wr,
                                              const float* __restrict__ br,
                                              float* __restrict__ gu,
                                              float* __restrict__ gr)
{
    PHASE_PROLOG
    const int gate = blockIdx.x >> 3;
    const int col0 = (blockIdx.x & 7) * 64;
    #pragma unroll
    for (int l = 0; l < 4; ++l) {
        int idx = tid + l * 256;
        int r = idx >> 7, c = (idx & 127) * 4;
        int tok = toks[(m0 + r) * TT + t];
        *(float4*)&As[0][r][c] = *(const float4*)&emb[(size_t)tok * 512 + c];
        *(float4*)&As[1][r][c] = *(const float4*)&h[(size_t)(m0 + r) * 512 + c];
    }
    __syncthreads();
    const float* W = gate ? Wr : Wu;
    const int col = col0 + n4 * 4;
    red[tid] = core512(W + (size_t)(kh * 512) * 512 + col, As[kh][mi]);
    __syncthreads();
    if (tid < 128) {
        float4 s = red[tid], s2 = red[tid + 128];
        s.x += s2.x; s.y += s2.y; s.z += s2.z; s.w += s2.w;
        int m = m0 + (tid >> 4), cc = col0 + (tid & 15) * 4;
        const float* bias = gate ? br : bu;
        float4 b4 = *(const float4*)&bias[cc];
        float4 o;
        o.x = sigmoidf_(s.x + b4.x); o.y = sigmoidf_(s.y + b4.y);
        o.z = sigmoidf_(s.z + b4.z); o.w = sigmoidf_(s.w + b4.w);
        *(float4*)&((gate ? gr : gu)[(size_t)m * 512 + cc]) = o;
    }
}

// L0 cand+combine: hh = tanh([emb, gr*h] @ Wc0 + bc0); s0new = gu*h+(1-gu)*hh
// grid (8, 16)
__global__ __launch_bounds__(256) void k_p2l0(const float* __restrict__ h,
                                              const float* __restrict__ emb,
                                              const int* __restrict__ toks, int t,
                                              const float* __restrict__ Wc,
                                              const float* __restrict__ bc,
                                              const float* __restrict__ gu,
                                              const float* __restrict__ gr,
                                              float* __restrict__ hnew)
{
    PHASE_PROLOG
    const int col0 = blockIdx.x * 64;
    #pragma unroll
    for (int l = 0; l < 4; ++l) {
        int idx = tid + l * 256;
        int r = idx >> 7, c = (idx & 127) * 4;
        int tok = toks[(m0 + r) * TT + t];
        *(float4*)&As[0][r][c] = *(const float4*)&emb[(size_t)tok * 512 + c];
        float4 hv = *(const float4*)&h[(size_t)(m0 + r) * 512 + c];
        float4 gv = *(const float4*)&gr[(size_t)(m0 + r) * 512 + c];
        hv.x *= gv.x; hv.y *= gv.y; hv.z *= gv.z; hv.w *= gv.w;
        *(float4*)&As[1][r][c] = hv;
    }
    __syncthreads();
    const int col = col0 + n4 * 4;
    red[tid] = core512(Wc + (size_t)(kh * 512) * 512 + col, As[kh][mi]);
    __syncthreads();
    if (tid < 128) {
        float4 s = red[tid], s2 = red[tid + 128];
        s.x += s2.x; s.y += s2.y; s.z += s2.z; s.w += s2.w;
        int m = m0 + (tid >> 4), cc = col0 + (tid & 15) * 4;
        size_t base = (size_t)m * 512 + cc;
        float4 b4 = *(const float4*)&bc[cc];
        float4 g  = *(const float4*)&gu[base];
        float4 hv = *(const float4*)&h[base];
        float4 o;
        o.x = g.x * hv.x + (1.f - g.x) * tanhf(s.x + b4.x);
        o.y = g.y * hv.y + (1.f - g.y) * tanhf(s.y + b4.y);
        o.z = g.z * hv.z + (1.f - g.z) * tanhf(s.z + b4.z);
        o.w = g.w * hv.w + (1.f - g.w) * tanhf(s.w + b4.w);
        *(float4*)&hnew[base] = o;
    }
}

// L1 gates: gu|gr = sigmoid([s0new, h1] @ {Wu1|Wr1} + {bu1|br1}). grid (16,16)
__global__ __launch_bounds__(256) void k_p1l1(const float* __restrict__ s0n,
                                              const float* __restrict__ h1,
                                              const float* __restrict__ Wu,
                                              const float* __restrict__ bu,
                                              const float* __restrict__ Wr,
                                              const float* __restrict__ br,
                                              float* __restrict__ gu,
                                              float* __restrict__ gr)
{
    PHASE_PROLOG
    const int gate = blockIdx.x >> 3;
    const int col0 = (blockIdx.x & 7) * 64;
    #pragma unroll
    for (int l = 0; l < 4; ++l) {
        int idx = tid + l * 256;
        int r = idx >> 7, c = (idx & 127) * 4;
        *(float4*)&As[0][r][c] = *(const float4*)&s0n[(size_t)(m0 + r) * 512 + c];
        *(float4*)&As[1][r][c] = *(const float4*)&h1[(size_t)(m0 + r) * 512 + c];
    }
    __syncthreads();
    const float* W = gate ? Wr : Wu;
    const int col = col0 + n4 * 4;
    red[tid] = core512(W + (size_t)(kh * 512) * 512 + col, As[kh][mi]);
    __syncthreads();
    if (tid < 128) {
        float4 s = red[tid], s2 = red[tid + 128];
        s.x += s2.x; s.y += s2.y; s.z += s2.z; s.w += s2.w;
        int m = m0 + (tid >> 4), cc = col0 + (tid & 15) * 4;
        const float* bias = gate ? br : bu;
        float4 b4 = *(const float4*)&bias[cc];
        float4 o;
        o.x = sigmoidf_(s.x + b4.x); o.y = sigmoidf_(s.y + b4.y);
        o.z = sigmoidf_(s.z + b4.z); o.w = sigmoidf_(s.w + b4.w);
        *(float4*)&((gate ? gr : gu)[(size_t)m * 512 + cc]) = o;
    }
}

// L1 cand+combine: hh = tanh([s0new, gr*h1] @ Wc1 + bc1);
// s1new = gu*h1+(1-gu)*hh -> hnew (fp32) and s1bf row (bf16). grid (8,16)
__global__ __launch_bounds__(256) void k_p2l1(const float* __restrict__ h1,
                                              const float* __restrict__ s0n,
                                              const float* __restrict__ Wc,
                                              const float* __restrict__ bc,
                                              const float* __restrict__ gu,
                                              const float* __restrict__ gr,
                                              float* __restrict__ hnew,
                                              unsigned short* __restrict__ s1bf_t)
{
    PHASE_PROLOG
    const int col0 = blockIdx.x * 64;
    #pragma unroll
    for (int l = 0; l < 4; ++l) {
        int idx = tid + l * 256;
        int r = idx >> 7, c = (idx & 127) * 4;
        *(float4*)&As[0][r][c] = *(const float4*)&s0n[(size_t)(m0 + r) * 512 + c];
        float4 hv = *(const float4*)&h1[(size_t)(m0 + r) * 512 + c];
        float4 gv = *(const float4*)&gr[(size_t)(m0 + r) * 512 + c];
        hv.x *= gv.x; hv.y *= gv.y; hv.z *= gv.z; hv.w *= gv.w;
        *(float4*)&As[1][r][c] = hv;
    }
    __syncthreads();
    const int col = col0 + n4 * 4;
    red[tid] = core512(Wc + (size_t)(kh * 512) * 512 + col, As[kh][mi]);
    __syncthreads();
    if (tid < 128) {
        float4 s = red[tid], s2 = red[tid + 128];
        s.x += s2.x; s.y += s2.y; s.z += s2.z; s.w += s2.w;
        int m = m0 + (tid >> 4), cc = col0 + (tid & 15) * 4;
        size_t base = (size_t)m * 512 + cc;
        float4 b4 = *(const float4*)&bc[cc];
        float4 g  = *(const float4*)&gu[base];
        float4 hv = *(const float4*)&h1[base];
        float4 o;
        o.x = g.x * hv.x + (1.f - g.x) * tanhf(s.x + b4.x);
        o.y = g.y * hv.y + (1.f - g.y) * tanhf(s.y + b4.y);
        o.z = g.z * hv.z + (1.f - g.z) * tanhf(s.z + b4.z);
        o.w = g.w * hv.w + (1.f - g.w) * tanhf(s.w + b4.w);
        *(float4*)&hnew[base] = o;
        ushort4 u;
        u.x = f2bfu(o.x); u.y = f2bfu(o.y); u.z = f2bfu(o.z); u.w = f2bfu(o.w);
        *(ushort4*)&s1bf_t[base] = u;
    }
}

// =====================================================================
// Wout transpose+convert: fp32 [512][10000] -> bf16 [10000][512].
// grid (313, 16), 32x32 tiles.
// =====================================================================
__global__ __launch_bounds__(256) void k_wT(const float* __restrict__ W,
                                            unsigned short* __restrict__ wT)
{
    __shared__ float T[32][33];
    const int tid = threadIdx.x;
    const int n0 = blockIdx.x * 32, k0 = blockIdx.y * 32;
    {
        int r = tid >> 3, c4 = (tid & 7) * 4;
        float4 v = {0.f, 0.f, 0.f, 0.f};
        if (n0 + c4 + 3 < VOCAB)
            v = *(const float4*)&W[(size_t)(k0 + r) * VOCAB + n0 + c4];
        else {
            if (n0 + c4 + 0 < VOCAB) v.x = W[(size_t)(k0 + r) * VOCAB + n0 + c4 + 0];
            if (n0 + c4 + 1 < VOCAB) v.y = W[(size_t)(k0 + r) * VOCAB + n0 + c4 + 1];
            if (n0 + c4 + 2 < VOCAB) v.z = W[(size_t)(k0 + r) * VOCAB + n0 + c4 + 2];
        }
        T[r][c4 + 0] = v.x; T[r][c4 + 1] = v.y; T[r][c4 + 2] = v.z; T[r][c4 + 3] = v.w;
    }
    __syncthreads();
    {
        int rn = tid >> 3, c4 = (tid & 7) * 4;
        if (n0 + rn < VOCAB) {
            ushort4 u;
            u.x = f2bfu(T[c4 + 0][rn]);
            u.y = f2bfu(T[c4 + 1][rn]);
            u.z = f2bfu(T[c4 + 2][rn]);
            u.w = f2bfu(T[c4 + 3][rn]);
            *(ushort4*)&wT[(size_t)(n0 + rn) * 512 + k0 + c4] = u;
        }
    }
}

// =====================================================================
// MFMA bf16 logits: C[m,n] = A[m,:] @ WoutT[n,:] + bout[n], m = t*128+b.
// A = s1bf [3200][512] bf16, B = wT [10000][512] bf16 (both [.][k]).
// BM=128, BN=128, BK=32; 4 waves, wave = 128m x 32n. grid (79, 25).
// =====================================================================
__global__ __launch_bounds__(256) void k_logits(const unsigned short* __restrict__ A,
                                                const unsigned short* __restrict__ Bt,
                                                const float* __restrict__ bias,
                                                float* __restrict__ out)
{
    __shared__ unsigned short As16[128][40];
    __shared__ unsigned short Bs16[128][40];
    const int tid = threadIdx.x;
    const int lane = tid & 63, w = tid >> 6;
    const int quad = lane >> 4, l15 = lane & 15;
    const int n0 = blockIdx.x * 128, m0 = blockIdx.y * 128;

    f32x4 acc[8][2];
    #pragma unroll
    for (int i = 0; i < 8; ++i)
        #pragma unroll
        for (int j = 0; j < 2; ++j) acc[i][j] = (f32x4){0.f, 0.f, 0.f, 0.f};

    for (int k0 = 0; k0 < 512; k0 += 32) {
        #pragma unroll
        for (int l = 0; l < 4; ++l) {
            int idx = tid + l * 256;
            int r = idx >> 3, c8 = (idx & 7) * 4;
            *(ushort4*)&As16[r][c8] =
                *(const ushort4*)&A[(size_t)(m0 + r) * 512 + k0 + c8];
            ushort4 bv = {0, 0, 0, 0};
            if (n0 + r < VOCAB)
                bv = *(const ushort4*)&Bt[(size_t)(n0 + r) * 512 + k0 + c8];
            *(ushort4*)&Bs16[r][c8] = bv;
        }
        __syncthreads();
        bf16x8 bfrag[2];
        #pragma unroll
        for (int nt = 0; nt < 2; ++nt)
            bfrag[nt] = *(const bf16x8*)&Bs16[w * 32 + nt * 16 + l15][quad * 8];
        #pragma unroll
        for (int mt = 0; mt < 8; ++mt) {
            bf16x8 afrag = *(const bf16x8*)&As16[mt * 16 + l15][quad * 8];
            acc[mt][0] = __builtin_amdgcn_mfma_f32_16x16x32_bf16(afrag, bfrag[0], acc[mt][0], 0, 0, 0);
            acc[mt][1] = __builtin_amdgcn_mfma_f32_16x16x32_bf16(afrag, bfrag[1], acc[mt][1], 0, 0, 0);
        }
        __syncthreads();
    }

    #pragma unroll
    for (int nt = 0; nt < 2; ++nt) {
        int n = n0 + w * 32 + nt * 16 + l15;
        if (n < VOCAB) {
            float bo = bias[n];
            #pragma unroll
            for (int mt = 0; mt < 8; ++mt) {
                #pragma unroll
                for (int r = 0; r < 4; ++r) {
                    int m = m0 + mt * 16 + quad * 4 + r;
                    int tt = m >> 7, bb = m & 127;
                    out[(size_t)bb * (TT * VOCAB) + (size_t)tt * VOCAB + n] =
                        acc[mt][nt][r] + bo;
                }
            }
        }
    }
}

__global__ void k_states(const float* __restrict__ s0, const float* __restrict__ s1,
                         float* __restrict__ out)
{
    int i = blockIdx.x * 256 + threadIdx.x;
    if (i < BB * HIDD) {
        out[i] = s0[i];
        out[BB * HIDD + i] = s1[i];
    }
}

extern "C" void kernel_launch(void* const* d_in, const int* in_sizes, int n_in,
                              void* d_out, int out_size, void* d_ws, size_t ws_size,
                              hipStream_t stream)
{
    const float* vgg  = (const float*)d_in[0];
    const int*   toks = (const int*)d_in[1];
    const float* emb  = (const float*)d_in[3];
    const float* Win  = (const float*)d_in[4];
    const float* bin  = (const float*)d_in[5];
    const float* Wu0  = (const float*)d_in[6];
    const float* bu0  = (const float*)d_in[7];
    const float* Wr0  = (const float*)d_in[8];
    const float* br0  = (const float*)d_in[9];
    const float* Wc0  = (const float*)d_in[10];
    const float* bc0  = (const float*)d_in[11];
    const float* Wu1  = (const float*)d_in[12];
    const float* bu1  = (const float*)d_in[13];
    const float* Wr1  = (const float*)d_in[14];
    const float* br1  = (const float*)d_in[15];
    const float* Wc1  = (const float*)d_in[16];
    const float* bc1  = (const float*)d_in[17];
    const float* Wout = (const float*)d_in[18];
    const float* bout = (const float*)d_in[19];

    float* ws = (float*)d_ws;
    float* s0a = ws;                        // 6 x 128*512 fp32
    float* s0b = s0a + BB * HIDD;
    float* s1a = s0b + BB * HIDD;
    float* s1b = s1a + BB * HIDD;
    float* gu  = s1b + BB * HIDD;
    float* gr  = gu + BB * HIDD;
    unsigned short* s1bf = (unsigned short*)(gr + BB * HIDD);   // 3200*512 bf16
    unsigned short* wT   = s1bf + (size_t)TT * BB * HIDD;       // 10000*512 bf16

    float* out = (float*)d_out;

    k_wT<<<dim3(313, 16), 256, 0, stream>>>(Wout, wT);
    k_h0<<<dim3(8, 8), 256, 0, stream>>>(vgg, Win, bin, s0a, s1a);

    for (int t = 0; t < TT; ++t) {
        k_p1l0<<<dim3(16, 16), 256, 0, stream>>>(s0a, emb, toks, t,
                                                 Wu0, bu0, Wr0, br0, gu, gr);
        k_p2l0<<<dim3(8, 16), 256, 0, stream>>>(s0a, emb, toks, t,
                                                Wc0, bc0, gu, gr, s0b);
        k_p1l1<<<dim3(16, 16), 256, 0, stream>>>(s0b, s1a,
                                                 Wu1, bu1, Wr1, br1, gu, gr);
        k_p2l1<<<dim3(8, 16), 256, 0, stream>>>(s1a, s0b, Wc1, bc1, gu, gr,
                                                s1b, s1bf + (size_t)t * BB * HIDD);
        float* tmp;
        tmp = s0a; s0a = s0b; s0b = tmp;
        tmp = s1a; s1a = s1b; s1b = tmp;
    }

    k_logits<<<dim3(79, 25), 256, 0, stream>>>(s1bf, wT, bout, out);

    k_states<<<dim3((BB * HIDD + 255) / 256), 256, 0, stream>>>(
        s0a, s1a, out + (size_t)TT * BB * VOCAB);
}

// Round 5
// 1755.821 us; speedup vs baseline: 2.9540x; 1.2208x over previous
//
#include <hip/hip_runtime.h>
#include <hip/hip_bf16.h>

#define BB 128
#define TT 25
#define VOCAB 10000
#define HIDD 512

typedef __hip_bfloat16 bf16;
typedef short bf16x8 __attribute__((ext_vector_type(8)));
typedef float f32x4 __attribute__((ext_vector_type(4)));

__device__ __forceinline__ float sigmoidf_(float x) { return 1.0f / (1.0f + __expf(-x)); }

__device__ __forceinline__ float4 f4_fma(float s, float4 w, float4 a) {
    a.x += s * w.x; a.y += s * w.y; a.z += s * w.z; a.w += s * w.w;
    return a;
}

__device__ __forceinline__ unsigned short f2bfu(float x) {
    bf16 h = __float2bfloat16(x);
    return *reinterpret_cast<unsigned short*>(&h);
}

// Per-thread 128-k accumulation over 4 cols; 8 loads in flight (x2 unroll).
__device__ __forceinline__ float4 core128(const float* __restrict__ Wp,
                                          const float* __restrict__ arow)
{
    float4 acc = {0.f, 0.f, 0.f, 0.f};
    #pragma unroll 2
    for (int k = 0; k < 128; k += 8) {
        float4 w[8];
        #pragma unroll
        for (int j = 0; j < 8; ++j)
            w[j] = *(const float4*)(Wp + (size_t)(k + j) * 512);
        #pragma unroll
        for (int j = 0; j < 8; ++j)
            acc = f4_fma(arow[k + j], w[j], acc);
    }
    return acc;
}

// Thread layout (256 thr): n4 = tid&15 (16 float4 = 64 cols),
// mi = (tid>>4)&1 (2 m-rows), kh = tid>>5 (8-way K-split of 1024).
// sl = kh>>2 picks slab (x vs h), kl0 = (kh&3)*128 the K-quarter.
#define PHASE2 \
    __shared__ float As[2][2][516]; \
    __shared__ float4 red[256]; \
    const int tid = threadIdx.x; \
    const int n4 = tid & 15, mi = (tid >> 4) & 1, kh = tid >> 5; \
    const int sl = kh >> 2, kl0 = (kh & 3) * 128; \
    const int m0 = blockIdx.y * 2;

#define PHASE_REDUCE(SVAR) \
    __syncthreads(); \
    float4 SVAR; \
    if (tid < 32) { \
        SVAR = red[tid]; \
        _Pragma("unroll") \
        for (int j = 1; j < 8; ++j) { \
            float4 p = red[tid + 32 * j]; \
            SVAR.x += p.x; SVAR.y += p.y; SVAR.z += p.z; SVAR.w += p.w; \
        } \
    }

// =====================================================================
// h0 partial: vgg[128,4096] @ W_in[4096,512], K split over 4 blocks (z).
// grid (8, 64, 4).  partial[kq][128][512]
// =====================================================================
__global__ __launch_bounds__(256) void k_h0p(const float* __restrict__ A,
                                             const float* __restrict__ W,
                                             float* __restrict__ partial)
{
    __shared__ float As2[2][1032];
    __shared__ float4 red[256];
    const int tid = threadIdx.x;
    const int n4 = tid & 15, mi = (tid >> 4) & 1, kh = tid >> 5;
    const int m0 = blockIdx.y * 2, col0 = blockIdx.x * 64, kq = blockIdx.z;

    #pragma unroll
    for (int l = 0; l < 2; ++l) {
        int idx = tid + l * 256;
        int r = idx >> 8, c4 = (idx & 255) * 4;
        *(float4*)&As2[r][c4] =
            *(const float4*)&A[(size_t)(m0 + r) * 4096 + kq * 1024 + c4];
    }
    __syncthreads();
    red[tid] = core128(W + (size_t)(kq * 1024 + kh * 128) * 512 + col0 + n4 * 4,
                       &As2[mi][kh * 128]);
    PHASE_REDUCE(s)
    if (tid < 32) {
        int m = m0 + (tid >> 4), cc = col0 + (tid & 15) * 4;
        *(float4*)&partial[((size_t)kq * 128 + m) * 512 + cc] = s;
    }
}

// h0 finalize: sum 4 partials + bias, tanh, write s0 & s1. grid (64)
__global__ void k_h0f(const float* __restrict__ partial,
                      const float* __restrict__ bias,
                      float* __restrict__ s0, float* __restrict__ s1)
{
    int i = blockIdx.x * 256 + threadIdx.x;   // float4 index over 128*512/4
    size_t e = (size_t)i * 4;
    int cc = (int)(e & 511);
    float4 s = *(const float4*)&partial[e];
    #pragma unroll
    for (int j = 1; j < 4; ++j) {
        float4 p = *(const float4*)&partial[(size_t)j * 128 * 512 + e];
        s.x += p.x; s.y += p.y; s.z += p.z; s.w += p.w;
    }
    float4 b4 = *(const float4*)&bias[cc];
    float4 o;
    o.x = tanhf(s.x + b4.x); o.y = tanhf(s.y + b4.y);
    o.z = tanhf(s.z + b4.z); o.w = tanhf(s.w + b4.w);
    *(float4*)&s0[e] = o;
    *(float4*)&s1[e] = o;
}

// =====================================================================
// L0 gates: gu|gr = sigmoid([emb(tok), h] @ {Wu0|Wr0} + b). grid (16, 64)
// =====================================================================
__global__ __launch_bounds__(256) void k_p1l0(const float* __restrict__ h,
                                              const float* __restrict__ emb,
                                              const int* __restrict__ toks, int t,
                                              const float* __restrict__ Wu,
                                              const float* __restrict__ bu,
                                              const float* __restrict__ Wr,
                                              const float* __restrict__ br,
                                              float* __restrict__ gu,
                                              float* __restrict__ gr)
{
    PHASE2
    const int gate = blockIdx.x >> 3;
    const int col0 = (blockIdx.x & 7) * 64;
    #pragma unroll
    for (int l = 0; l < 2; ++l) {
        int idx = tid + l * 256;
        int slb = idx >> 8, r = (idx >> 7) & 1, c = (idx & 127) * 4;
        float4 v;
        if (slb == 0) {
            int tok = toks[(m0 + r) * TT + t];
            v = *(const float4*)&emb[(size_t)tok * 512 + c];
        } else {
            v = *(const float4*)&h[(size_t)(m0 + r) * 512 + c];
        }
        *(float4*)&As[slb][r][c] = v;
    }
    __syncthreads();
    const float* W = gate ? Wr : Wu;
    red[tid] = core128(W + (size_t)(sl * 512 + kl0) * 512 + col0 + n4 * 4,
                       &As[sl][mi][kl0]);
    PHASE_REDUCE(s)
    if (tid < 32) {
        int m = m0 + (tid >> 4), cc = col0 + (tid & 15) * 4;
        const float* bias = gate ? br : bu;
        float4 b4 = *(const float4*)&bias[cc];
        float4 o;
        o.x = sigmoidf_(s.x + b4.x); o.y = sigmoidf_(s.y + b4.y);
        o.z = sigmoidf_(s.z + b4.z); o.w = sigmoidf_(s.w + b4.w);
        *(float4*)&((gate ? gr : gu)[(size_t)m * 512 + cc]) = o;
    }
}

// =====================================================================
// L0 cand+combine: hh = tanh([emb, gr*h] @ Wc0 + bc0);
// s0new = gu*h + (1-gu)*hh.  grid (8, 64)
// =====================================================================
__global__ __launch_bounds__(256) void k_p2l0(const float* __restrict__ h,
                                              const float* __restrict__ emb,
                                              const int* __restrict__ toks, int t,
                                              const float* __restrict__ Wc,
                                              const float* __restrict__ bc,
                                              const float* __restrict__ gu,
                                              const float* __restrict__ gr,
                                              float* __restrict__ hnew)
{
    PHASE2
    const int col0 = blockIdx.x * 64;
    #pragma unroll
    for (int l = 0; l < 2; ++l) {
        int idx = tid + l * 256;
        int slb = idx >> 8, r = (idx >> 7) & 1, c = (idx & 127) * 4;
        float4 v;
        if (slb == 0) {
            int tok = toks[(m0 + r) * TT + t];
            v = *(const float4*)&emb[(size_t)tok * 512 + c];
        } else {
            float4 hv = *(const float4*)&h[(size_t)(m0 + r) * 512 + c];
            float4 gv = *(const float4*)&gr[(size_t)(m0 + r) * 512 + c];
            v.x = hv.x * gv.x; v.y = hv.y * gv.y;
            v.z = hv.z * gv.z; v.w = hv.w * gv.w;
        }
        *(float4*)&As[slb][r][c] = v;
    }
    __syncthreads();
    red[tid] = core128(Wc + (size_t)(sl * 512 + kl0) * 512 + col0 + n4 * 4,
                       &As[sl][mi][kl0]);
    PHASE_REDUCE(s)
    if (tid < 32) {
        int m = m0 + (tid >> 4), cc = col0 + (tid & 15) * 4;
        size_t base = (size_t)m * 512 + cc;
        float4 b4 = *(const float4*)&bc[cc];
        float4 g  = *(const float4*)&gu[base];
        float4 hv = *(const float4*)&h[base];
        float4 o;
        o.x = g.x * hv.x + (1.f - g.x) * tanhf(s.x + b4.x);
        o.y = g.y * hv.y + (1.f - g.y) * tanhf(s.y + b4.y);
        o.z = g.z * hv.z + (1.f - g.z) * tanhf(s.z + b4.z);
        o.w = g.w * hv.w + (1.f - g.w) * tanhf(s.w + b4.w);
        *(float4*)&hnew[base] = o;
    }
}

// =====================================================================
// L1 gates: gu|gr = sigmoid([s0new, h1] @ {Wu1|Wr1} + b). grid (16, 64)
// =====================================================================
__global__ __launch_bounds__(256) void k_p1l1(const float* __restrict__ s0n,
                                              const float* __restrict__ h1,
                                              const float* __restrict__ Wu,
                                              const float* __restrict__ bu,
                                              const float* __restrict__ Wr,
                                              const float* __restrict__ br,
                                              float* __restrict__ gu,
                                              float* __restrict__ gr)
{
    PHASE2
    const int gate = blockIdx.x >> 3;
    const int col0 = (blockIdx.x & 7) * 64;
    #pragma unroll
    for (int l = 0; l < 2; ++l) {
        int idx = tid + l * 256;
        int slb = idx >> 8, r = (idx >> 7) & 1, c = (idx & 127) * 4;
        const float* src = slb == 0 ? &s0n[(size_t)(m0 + r) * 512 + c]
                                    : &h1[(size_t)(m0 + r) * 512 + c];
        *(float4*)&As[slb][r][c] = *(const float4*)src;
    }
    __syncthreads();
    const float* W = gate ? Wr : Wu;
    red[tid] = core128(W + (size_t)(sl * 512 + kl0) * 512 + col0 + n4 * 4,
                       &As[sl][mi][kl0]);
    PHASE_REDUCE(s)
    if (tid < 32) {
        int m = m0 + (tid >> 4), cc = col0 + (tid & 15) * 4;
        const float* bias = gate ? br : bu;
        float4 b4 = *(const float4*)&bias[cc];
        float4 o;
        o.x = sigmoidf_(s.x + b4.x); o.y = sigmoidf_(s.y + b4.y);
        o.z = sigmoidf_(s.z + b4.z); o.w = sigmoidf_(s.w + b4.w);
        *(float4*)&((gate ? gr : gu)[(size_t)m * 512 + cc]) = o;
    }
}

// =====================================================================
// L1 cand+combine: hh = tanh([s0new, gr*h1] @ Wc1 + bc1);
// s1new = gu*h1+(1-gu)*hh -> hnew fp32 + s1bf row bf16.  grid (8, 64)
// =====================================================================
__global__ __launch_bounds__(256) void k_p2l1(const float* __restrict__ h1,
                                              const float* __restrict__ s0n,
                                              const float* __restrict__ Wc,
                                              const float* __restrict__ bc,
                                              const float* __restrict__ gu,
                                              const float* __restrict__ gr,
                                              float* __restrict__ hnew,
                                              unsigned short* __restrict__ s1bf_t)
{
    PHASE2
    const int col0 = blockIdx.x * 64;
    #pragma unroll
    for (int l = 0; l < 2; ++l) {
        int idx = tid + l * 256;
        int slb = idx >> 8, r = (idx >> 7) & 1, c = (idx & 127) * 4;
        float4 v;
        if (slb == 0) {
            v = *(const float4*)&s0n[(size_t)(m0 + r) * 512 + c];
        } else {
            float4 hv = *(const float4*)&h1[(size_t)(m0 + r) * 512 + c];
            float4 gv = *(const float4*)&gr[(size_t)(m0 + r) * 512 + c];
            v.x = hv.x * gv.x; v.y = hv.y * gv.y;
            v.z = hv.z * gv.z; v.w = hv.w * gv.w;
        }
        *(float4*)&As[slb][r][c] = v;
    }
    __syncthreads();
    red[tid] = core128(Wc + (size_t)(sl * 512 + kl0) * 512 + col0 + n4 * 4,
                       &As[sl][mi][kl0]);
    PHASE_REDUCE(s)
    if (tid < 32) {
        int m = m0 + (tid >> 4), cc = col0 + (tid & 15) * 4;
        size_t base = (size_t)m * 512 + cc;
        float4 b4 = *(const float4*)&bc[cc];
        float4 g  = *(const float4*)&gu[base];
        float4 hv = *(const float4*)&h1[base];
        float4 o;
        o.x = g.x * hv.x + (1.f - g.x) * tanhf(s.x + b4.x);
        o.y = g.y * hv.y + (1.f - g.y) * tanhf(s.y + b4.y);
        o.z = g.z * hv.z + (1.f - g.z) * tanhf(s.z + b4.z);
        o.w = g.w * hv.w + (1.f - g.w) * tanhf(s.w + b4.w);
        *(float4*)&hnew[base] = o;
        ushort4 u;
        u.x = f2bfu(o.x); u.y = f2bfu(o.y); u.z = f2bfu(o.z); u.w = f2bfu(o.w);
        *(ushort4*)&s1bf_t[base] = u;
    }
}

// =====================================================================
// Wout transpose+convert: fp32 [512][10000] -> bf16 [10000][512].
// =====================================================================
__global__ __launch_bounds__(256) void k_wT(const float* __restrict__ W,
                                            unsigned short* __restrict__ wT)
{
    __shared__ float T[32][33];
    const int tid = threadIdx.x;
    const int n0 = blockIdx.x * 32, k0 = blockIdx.y * 32;
    {
        int r = tid >> 3, c4 = (tid & 7) * 4;
        float4 v = {0.f, 0.f, 0.f, 0.f};
        if (n0 + c4 + 3 < VOCAB)
            v = *(const float4*)&W[(size_t)(k0 + r) * VOCAB + n0 + c4];
        else {
            if (n0 + c4 + 0 < VOCAB) v.x = W[(size_t)(k0 + r) * VOCAB + n0 + c4 + 0];
            if (n0 + c4 + 1 < VOCAB) v.y = W[(size_t)(k0 + r) * VOCAB + n0 + c4 + 1];
            if (n0 + c4 + 2 < VOCAB) v.z = W[(size_t)(k0 + r) * VOCAB + n0 + c4 + 2];
        }
        T[r][c4 + 0] = v.x; T[r][c4 + 1] = v.y; T[r][c4 + 2] = v.z; T[r][c4 + 3] = v.w;
    }
    __syncthreads();
    {
        int rn = tid >> 3, c4 = (tid & 7) * 4;
        if (n0 + rn < VOCAB) {
            ushort4 u;
            u.x = f2bfu(T[c4 + 0][rn]);
            u.y = f2bfu(T[c4 + 1][rn]);
            u.z = f2bfu(T[c4 + 2][rn]);
            u.w = f2bfu(T[c4 + 3][rn]);
            *(ushort4*)&wT[(size_t)(n0 + rn) * 512 + k0 + c4] = u;
        }
    }
}

// =====================================================================
// MFMA bf16 logits (unchanged from round 4): grid (79, 25)
// =====================================================================
__global__ __launch_bounds__(256) void k_logits(const unsigned short* __restrict__ A,
                                                const unsigned short* __restrict__ Bt,
                                                const float* __restrict__ bias,
                                                float* __restrict__ out)
{
    __shared__ unsigned short As16[128][40];
    __shared__ unsigned short Bs16[128][40];
    const int tid = threadIdx.x;
    const int lane = tid & 63, w = tid >> 6;
    const int quad = lane >> 4, l15 = lane & 15;
    const int n0 = blockIdx.x * 128, m0 = blockIdx.y * 128;

    f32x4 acc[8][2];
    #pragma unroll
    for (int i = 0; i < 8; ++i)
        #pragma unroll
        for (int j = 0; j < 2; ++j) acc[i][j] = (f32x4){0.f, 0.f, 0.f, 0.f};

    for (int k0 = 0; k0 < 512; k0 += 32) {
        #pragma unroll
        for (int l = 0; l < 4; ++l) {
            int idx = tid + l * 256;
            int r = idx >> 3, c8 = (idx & 7) * 4;
            *(ushort4*)&As16[r][c8] =
                *(const ushort4*)&A[(size_t)(m0 + r) * 512 + k0 + c8];
            ushort4 bv = {0, 0, 0, 0};
            if (n0 + r < VOCAB)
                bv = *(const ushort4*)&Bt[(size_t)(n0 + r) * 512 + k0 + c8];
            *(ushort4*)&Bs16[r][c8] = bv;
        }
        __syncthreads();
        bf16x8 bfrag[2];
        #pragma unroll
        for (int nt = 0; nt < 2; ++nt)
            bfrag[nt] = *(const bf16x8*)&Bs16[w * 32 + nt * 16 + l15][quad * 8];
        #pragma unroll
        for (int mt = 0; mt < 8; ++mt) {
            bf16x8 afrag = *(const bf16x8*)&As16[mt * 16 + l15][quad * 8];
            acc[mt][0] = __builtin_amdgcn_mfma_f32_16x16x32_bf16(afrag, bfrag[0], acc[mt][0], 0, 0, 0);
            acc[mt][1] = __builtin_amdgcn_mfma_f32_16x16x32_bf16(afrag, bfrag[1], acc[mt][1], 0, 0, 0);
        }
        __syncthreads();
    }

    #pragma unroll
    for (int nt = 0; nt < 2; ++nt) {
        int n = n0 + w * 32 + nt * 16 + l15;
        if (n < VOCAB) {
            float bo = bias[n];
            #pragma unroll
            for (int mt = 0; mt < 8; ++mt) {
                #pragma unroll
                for (int r = 0; r < 4; ++r) {
                    int m = m0 + mt * 16 + quad * 4 + r;
                    int tt = m >> 7, bb = m & 127;
                    out[(size_t)bb * (TT * VOCAB) + (size_t)tt * VOCAB + n] =
                        acc[mt][nt][r] + bo;
                }
            }
        }
    }
}

__global__ void k_states(const float* __restrict__ s0, const float* __restrict__ s1,
                         float* __restrict__ out)
{
    int i = blockIdx.x * 256 + threadIdx.x;
    if (i < BB * HIDD) {
        out[i] = s0[i];
        out[BB * HIDD + i] = s1[i];
    }
}

extern "C" void kernel_launch(void* const* d_in, const int* in_sizes, int n_in,
                              void* d_out, int out_size, void* d_ws, size_t ws_size,
                              hipStream_t stream)
{
    const float* vgg  = (const float*)d_in[0];
    const int*   toks = (const int*)d_in[1];
    const float* emb  = (const float*)d_in[3];
    const float* Win  = (const float*)d_in[4];
    const float* bin  = (const float*)d_in[5];
    const float* Wu0  = (const float*)d_in[6];
    const float* bu0  = (const float*)d_in[7];
    const float* Wr0  = (const float*)d_in[8];
    const float* br0  = (const float*)d_in[9];
    const float* Wc0  = (const float*)d_in[10];
    const float* bc0  = (const float*)d_in[11];
    const float* Wu1  = (const float*)d_in[12];
    const float* bu1  = (const float*)d_in[13];
    const float* Wr1  = (const float*)d_in[14];
    const float* br1  = (const float*)d_in[15];
    const float* Wc1  = (const float*)d_in[16];
    const float* bc1  = (const float*)d_in[17];
    const float* Wout = (const float*)d_in[18];
    const float* bout = (const float*)d_in[19];

    float* ws = (float*)d_ws;
    float* s0a = ws;                        // 6 x 128*512 fp32
    float* s0b = s0a + BB * HIDD;
    float* s1a = s0b + BB * HIDD;
    float* s1b = s1a + BB * HIDD;
    float* gu  = s1b + BB * HIDD;
    float* gr  = gu + BB * HIDD;
    float* partial = gr + BB * HIDD;        // 4 x 128*512 fp32
    unsigned short* s1bf = (unsigned short*)(partial + 4 * BB * HIDD); // 3200*512 bf16
    unsigned short* wT   = s1bf + (size_t)TT * BB * HIDD;              // 10000*512 bf16

    float* out = (float*)d_out;

    k_wT<<<dim3(313, 16), 256, 0, stream>>>(Wout, wT);
    k_h0p<<<dim3(8, 64, 4), 256, 0, stream>>>(vgg, Win, partial);
    k_h0f<<<dim3(64), 256, 0, stream>>>(partial, bin, s0a, s1a);

    for (int t = 0; t < TT; ++t) {
        k_p1l0<<<dim3(16, 64), 256, 0, stream>>>(s0a, emb, toks, t,
                                                 Wu0, bu0, Wr0, br0, gu, gr);
        k_p2l0<<<dim3(8, 64), 256, 0, stream>>>(s0a, emb, toks, t,
                                                Wc0, bc0, gu, gr, s0b);
        k_p1l1<<<dim3(16, 64), 256, 0, stream>>>(s0b, s1a,
                                                 Wu1, bu1, Wr1, br1, gu, gr);
        k_p2l1<<<dim3(8, 64), 256, 0, stream>>>(s1a, s0b, Wc1, bc1, gu, gr,
                                                s1b, s1bf + (size_t)t * BB * HIDD);
        float* tmp;
        tmp = s0a; s0a = s0b; s0b = tmp;
        tmp = s1a; s1a = s1b; s1b = tmp;
    }

    k_logits<<<dim3(79, 25), 256, 0, stream>>>(s1bf, wT, bout, out);

    k_states<<<dim3((BB * HIDD + 255) / 256), 256, 0, stream>>>(
        s0a, s1a, out + (size_t)TT * BB * VOCAB);
}